// Round 8
// baseline (299.461 us; speedup 1.0000x reference)
//
#include <hip/hip_runtime.h>
#include <stdint.h>

// Problem constants: B=8, N=1024, IN_F=1024, E=256, H=4, A=64
typedef __attribute__((ext_vector_type(8))) short short8;
typedef __attribute__((ext_vector_type(4))) float f32x4;
typedef __attribute__((ext_vector_type(16))) float f32x16;

// WhF frag-tile layout (32x32 MFMA-B order; k1 epilogue -> k2):
//   element (hb, e, m): et=e>>5, e31=e&31, m16=m>>4, l5=(m>>3)&1, m7=m&7
//   u16 idx = ((hb*8+et)*64 + m16)*512 + (l5*32+e31)*8 + m7
// => one (et,m16) tile is 1KB contiguous in lane order (lane=l5*32+e31).

__device__ __forceinline__ float b2f(unsigned short u) {
    union { unsigned int i; float f; } v; v.i = ((unsigned int)u) << 16; return v.f;
}
__device__ __forceinline__ unsigned short f2b(float f) {
    union { float f; unsigned int i; } v; v.f = f;
    unsigned int u = v.i;
    u = (u + 0x7FFFu + ((u >> 16) & 1u)) >> 16;
    return (unsigned short)u;
}
// packed bf16 pair: lo=rne(a), hi=rne(b) — 1 instr replaces 2x f2b + pack
__device__ __forceinline__ unsigned int cvtpk(float a, float b) {
    unsigned int r;
    asm("v_cvt_pk_bf16_f32 %0, %1, %2" : "=v"(r) : "v"(a), "v"(b));
    return r;
}
__device__ __forceinline__ float blo(unsigned int u) {
    union { unsigned int i; float f; } v; v.i = u << 16; return v.f;
}
__device__ __forceinline__ float bhi(unsigned int u) {
    union { unsigned int i; float f; } v; v.i = u & 0xFFFF0000u; return v.f;
}
__device__ __forceinline__ void glds16(const void* g, const void* l) {
    __builtin_amdgcn_global_load_lds(
        (const __attribute__((address_space(1))) unsigned int*)g,
        (__attribute__((address_space(3))) unsigned int*)l, 16, 0, 0);
}

__device__ __forceinline__ void cvt8(const void* in, unsigned short* out,
                                     int f, int grp) {
    if (f) {
        ((ushort4*)out)[grp * 2]     = ((const ushort4*)in)[grp * 2];
        ((ushort4*)out)[grp * 2 + 1] = ((const ushort4*)in)[grp * 2 + 1];
    } else {
        const float4* p = (const float4*)in + (size_t)grp * 2;
        float4 a = p[0], b = p[1];
        ushort4 o0, o1;
        o0.x = f2b(a.x); o0.y = f2b(a.y); o0.z = f2b(a.z); o0.w = f2b(a.w);
        o1.x = f2b(b.x); o1.y = f2b(b.y); o1.z = f2b(b.z); o1.w = f2b(b.w);
        ((ushort4*)out)[grp * 2]     = o0;
        ((ushort4*)out)[grp * 2 + 1] = o1;
    }
}

// prep_all: single launch replacing prep+conv8+t2+zero+pack_adj.
// Blocks: [0,4096) x-convert | [4096,4352) W transpose | [4352,4416) zero f1/f2
//         | 4416 smalls+flag | [4417,4433) W_act transpose
//         | [4433,4561) fused pack_adj (maskT no longer aliases WT, so the
//           adj->bitmask pack overlaps the BW-bound conversion work and the
//           separate pack_adj launch (+gap, ~6us) is eliminated).
// Each block re-derives the dtype flag from x[0:64] (256B, L2-hot).
__global__ __launch_bounds__(256) void prep_all(
        const unsigned int* __restrict__ x4,
        const void* __restrict__ x, const void* __restrict__ W,
        const void* __restrict__ Wact,
        const void* __restrict__ a1, const void* __restrict__ a2,
        const void* __restrict__ bact,
        const int* __restrict__ adj,
        unsigned short* __restrict__ xb, unsigned short* __restrict__ WT,
        unsigned short* __restrict__ WactT,
        unsigned short* __restrict__ a1b, unsigned short* __restrict__ a2b,
        unsigned short* __restrict__ bactb,
        int* __restrict__ flag, float4* __restrict__ fz,
        unsigned int* __restrict__ maskT) {
    __shared__ unsigned int tile[64 * 65];
    __shared__ int sflag;
    int tid = threadIdx.x;
    int bid = blockIdx.x;
    if (bid >= 4433) {                                // fused pack_adj
        int lb = bid - 4433;                          // 0..127
        int w = tid >> 6, lane = tid & 63;
        // wave w handles 16 rows; row gr = b*1024+n, 16 ballot-words each.
#pragma unroll 1
        for (int rr = 0; rr < 16; rr++) {
            int gr = lb * 64 + w * 16 + rr;
            int b = gr >> 10, n = gr & 1023;
            const int* rowp = adj + (size_t)gr * 1024 + lane;
            unsigned int* mp = maskT + (size_t)b * 32 * 1024 + n;
#pragma unroll
            for (int k = 0; k < 16; k++) {
                unsigned long long m = __ballot(rowp[k * 64] > 0);
                if (lane == 0) {
                    mp[(size_t)(k * 2) * 1024]     = (unsigned int)m;
                    mp[(size_t)(k * 2 + 1) * 1024] = (unsigned int)(m >> 32);
                }
            }
        }
        return;
    }
    if (bid >= 4352 && bid < 4416) {                  // zero f1/f2 (256 KB)
        fz[(bid - 4352) * 256 + tid] = float4{0.f, 0.f, 0.f, 0.f};
        return;
    }
    if (tid < 64) {                                   // per-block dtype detect
        unsigned int wv = x4[tid];
        unsigned int e = (wv >> 7) & 0xFF;
        unsigned long long m = __ballot(e >= 100 && e <= 140);
        if (tid == 0) sflag = (__popcll(m) >= 48) ? 1 : 0;
    }
    __syncthreads();
    int f = sflag;

    if (bid < 4096) {                                 // x -> xb bf16
        cvt8(x, xb, f, bid * 256 + tid);
        return;
    }
    if (bid == 4416) {                                // smalls + flag publish
        if (tid == 0) flag[0] = f;
        if (tid < 128) cvt8(a1, a1b, f, tid);
        else           cvt8(a2, a2b, f, tid - 128);
        if (tid < 8)   cvt8(bact, bactb, f, tid);
        return;
    }
    // LDS-tiled transpose: W (256 blocks, C=256) or W_act (16 blocks, C=64).
    const void* in; unsigned short* out; int C, bt, c0, r0;
    if (bid < 4352) {
        int lb = bid - 4096;
        in = W; out = WT; C = 256;
        c0 = (lb & 3) * 64;
        r0 = ((lb >> 2) & 15) * 64;
        bt = lb >> 6;
    } else {
        int lb = bid - 4417;
        in = Wact; out = WactT; C = 64;
        c0 = 0; r0 = lb * 64; bt = 0;
    }
    int rl = tid >> 2;
    int cc = (tid & 3) * 16;
    size_t ibase = ((size_t)bt * 1024 + (r0 + rl)) * C + c0 + cc;
    unsigned short v[16];
    if (f) {
        const unsigned short* p = (const unsigned short*)in + ibase;
        short8 a = *(const short8*)p;
        short8 b = *(const short8*)(p + 8);
#pragma unroll
        for (int j = 0; j < 8; j++) { v[j] = (unsigned short)a[j]; v[8 + j] = (unsigned short)b[j]; }
    } else {
        const float* p = (const float*)in + ibase;
#pragma unroll
        for (int j = 0; j < 16; j++) v[j] = f2b(p[j]);
    }
#pragma unroll
    for (int j = 0; j < 16; j++)
        tile[(cc + j) * 65 + rl] = v[j];
    __syncthreads();
    int cl = tid >> 2;
    int rch = (tid & 3) * 16;
    unsigned short o[16];
#pragma unroll
    for (int j = 0; j < 16; j++)
        o[j] = (unsigned short)tile[cl * 65 + rch + j];
    unsigned short* op = out + ((size_t)bt * C + (c0 + cl)) * 1024 + r0 + rch;
#pragma unroll
    for (int q = 0; q < 4; q++) {
        ushort4 s; s.x = o[q*4]; s.y = o[q*4+1]; s.z = o[q*4+2]; s.w = o[q*4+3];
        ((ushort4*)op)[q] = s;
    }
}

// K1: Wh = x @ W[h] -> WhF frag-tile bf16 (32x32 layout). Epilogue also
// accumulates f1 = Wh.a1, f2 = Wh.a2 (pre-scaled by log2e) via shfl+atomics.
// Config = r3 best (128x128 tile, BK=64, grid dim3(8,64), XCD swizzle:
// FETCH 16.6MB verified). Static-array double-buffer (r7: 43->41us).
// CLOSED at ~41us: runs 420 TF, ABOVE the m97-structure small-problem
// reference curve (m102: 320 TF @ 16 GFLOP); further gains need the 256^2
// 8-phase schedule, which at this M,N gives only 0.5 blocks/CU. Do not
// re-attempt within-block pipelining (r4) or smaller tiles (r5).
__global__ __launch_bounds__(256) void k1_gemm(
        const unsigned short* __restrict__ x,
        const unsigned short* __restrict__ WT,      // [H][E=256][K=1024]
        unsigned short* __restrict__ WhF,
        const unsigned short* __restrict__ a1b,
        const unsigned short* __restrict__ a2b,
        float* __restrict__ f1, float* __restrict__ f2) {
    __shared__ unsigned short smA0[16 * 512];       // 16KB each
    __shared__ unsigned short smA1[16 * 512];
    __shared__ unsigned short smB0[16 * 512];
    __shared__ unsigned short smB1[16 * 512];
    int tid = threadIdx.x;
    int w = tid >> 6, lane = tid & 63;
    int lr = lane & 15, lq = lane >> 4;
    int lin = blockIdx.x + 8 * blockIdx.y;      // HW dispatch-linear id
    int xcd = lin & 7, kk = lin >> 3;
    int ct = kk >> 3;                           // col tile 0..7 (h, e-half)
    int rt = xcd * 8 + (kk & 7);                // row tile 0..63 (b = xcd)
    int col0 = ct * 128;
    int row0 = rt * 128;
    int h = col0 >> 8;
    int e_base = col0 & 255;
    int b = row0 >> 10;
    int m_base = row0 & 1023;
    int wr = w >> 1, wc = w & 1;

    f32x4 acc[4][4] = {};

    // stage one BK=64 tile pair (16KB A + 16KB B); 8 glds16 per thread
    auto stage = [&](unsigned short* dA, unsigned short* dB, int k0) {
#pragma unroll
        for (int s = 0; s < 4; s++) {
            int g = 4 * w + s;                  // g = kh*8 + rb
            int rb = g & 7, kh = g >> 3;
            const unsigned short* srcA =
                x + (size_t)(row0 + rb * 16 + lr) * 1024 + k0 + kh * 32 + lq * 8;
            glds16(srcA, dA + g * 512);
            const unsigned short* srcB =
                WT + (size_t)(h * 256 + e_base + rb * 16 + lr) * 1024
                   + k0 + kh * 32 + lq * 8;
            glds16(srcB, dB + g * 512);
        }
    };
    auto compute = [&](const unsigned short* sA, const unsigned short* sB) {
#pragma unroll
        for (int kh = 0; kh < 2; kh++) {
            short8 af[4], bf[4];
#pragma unroll
            for (int i = 0; i < 4; i++)
                af[i] = *(const short8*)&sA[(kh * 8 + wr * 4 + i) * 512 + lane * 8];
#pragma unroll
            for (int j = 0; j < 4; j++)
                bf[j] = *(const short8*)&sB[(kh * 8 + wc * 4 + j) * 512 + lane * 8];
#pragma unroll
            for (int i = 0; i < 4; i++)
#pragma unroll
                for (int j = 0; j < 4; j++)
                    acc[i][j] = __builtin_amdgcn_mfma_f32_16x16x32_bf16(
                        af[i], bf[j], acc[i][j], 0, 0, 0);
        }
    };

    stage(smA0, smB0, 0);
    __syncthreads();                            // buf0 ready
    for (int t = 0; t < 16; t += 2) {
        stage(smA1, smB1, (t + 1) * 64);        // t+1 <= 15 always
        compute(smA0, smB0);
        __syncthreads();                        // drain buf1 loads + LDS sync
        if (t + 2 < 16) stage(smA0, smB0, (t + 2) * 64);
        compute(smA1, smB1);
        __syncthreads();
    }

    // Epilogue 1: WhF frag-tile stores (32x32 layout).
    int hb = h * 8 + b;
#pragma unroll
    for (int i = 0; i < 4; i++) {
#pragma unroll
        for (int j = 0; j < 4; j++) {
            int e = e_base + (wc * 4 + j) * 16 + lr;
            int et = e >> 5, e31 = e & 31;
            int m16 = (m_base >> 4) + wr * 4 + i;
            ushort4 vs;
            vs.x = f2b(acc[i][j][0]);
            vs.y = f2b(acc[i][j][1]);
            vs.z = f2b(acc[i][j][2]);
            vs.w = f2b(acc[i][j][3]);
            size_t idx = ((size_t)((hb * 8 + et) * 64 + m16) * 512)
                         + ((lq >> 1) * 32 + e31) * 8 + (lq & 1) * 4;
            *(ushort4*)&WhF[idx] = vs;
        }
    }

    // Epilogue 2: f1/f2 partials via shfl-reduce over the 16-lane e-groups.
    const float LOG2E = 1.44269504f;
    float a1v[4], a2v[4];
#pragma unroll
    for (int j = 0; j < 4; j++) {
        int e = e_base + (wc * 4 + j) * 16 + lr;
        a1v[j] = b2f(a1b[h * 256 + e]);
        a2v[j] = b2f(a2b[h * 256 + e]);
    }
#pragma unroll
    for (int i = 0; i < 4; i++) {
#pragma unroll
        for (int reg = 0; reg < 4; reg++) {
            float s1 = 0.f, s2 = 0.f;
#pragma unroll
            for (int j = 0; j < 4; j++) {
                s1 += acc[i][j][reg] * a1v[j];
                s2 += acc[i][j][reg] * a2v[j];
            }
            s1 += __shfl_xor(s1, 1, 64); s2 += __shfl_xor(s2, 1, 64);
            s1 += __shfl_xor(s1, 2, 64); s2 += __shfl_xor(s2, 2, 64);
            s1 += __shfl_xor(s1, 4, 64); s2 += __shfl_xor(s2, 4, 64);
            s1 += __shfl_xor(s1, 8, 64); s2 += __shfl_xor(s2, 8, 64);
            if (lr == 0) {
                int m = m_base + (wr * 4 + i) * 16 + lq * 4 + reg;
                atomicAdd(&f1[hb * 1024 + m], s1 * LOG2E);
                atomicAdd(&f2[hb * 1024 + m], s2 * LOG2E);
            }
        }
    }
}

// K2: masked-softmax attention + P@Wh + ELU -> feat bf16.
// Block = 512 thr = 8 waves = 2 row-groups (64 rows) x 4 e-quarter waves.
// The 4 q-waves of a row-group SPLIT the 32 softmax columns (4 p/lane/iter)
// and exchange the bf16 P-tile through a double-buffered LDS tile. cvt_pk
// packs p-pairs in one instr; den accumulates the ROUNDED p halves.
// m-loop HAND-UNROLLED 2x (named bufA/bufB, literal ptile idx — rule #20).
// s_setprio(1/0) around MFMA clusters (T5: produce/consume wave role-split).
__global__ __launch_bounds__(512, 4) void k2_attn(
        const unsigned short* __restrict__ WhF,
        const unsigned int* __restrict__ maskT,     // [8][32][1024]
        const float* __restrict__ f1, const float* __restrict__ f2,
        unsigned short* __restrict__ feat) {
    __shared__ unsigned short ptile[2][2][32][40];  // [buf][rg][row][col pad40]
    __shared__ float dred[2][4][32];                // [rg][q][row]
    int tid = threadIdx.x;
    int w = tid >> 6, lane = tid & 63;
    int q = w & 3, wrg = w >> 2;
    int l5 = lane >> 5, l31 = lane & 31;
    int bid = blockIdx.x;
    int xcd = bid & 7, idx = bid >> 3;          // idx 0..63
    int hb = xcd + 8 * (idx >> 4);              // 4 hb per XCD, same b = xcd
    int rgb = idx & 15;                         // 16 row-blocks of 64
    int n0 = rgb * 64 + wrg * 32;
    int h = hb >> 3, b = hb & 7;
    int row = n0 + l31;
    float f1n = f1[hb * 1024 + row];            // already *log2e
    const unsigned short* whb = WhF + (size_t)(hb * 8 + q * 2) * 64 * 512
                                + lane * 8;
    const unsigned int* mrow = maskT + (size_t)b * 32 * 1024 + row;
    const float* f2p = f2 + hb * 1024 + q * 8 + l5 * 4;   // this lane's 4 cols
    int cshift = q * 8 + l5 * 4;                // col base within 32-block

    f32x16 acc[2] = {};                         // e = q*64 + et*32 + l31
    float den = 0.f;

    short8 bufA[2][2], bufB[2][2];              // [et][ks] — named, static idx
#pragma unroll
    for (int et = 0; et < 2; et++)
#pragma unroll
        for (int ks = 0; ks < 2; ks++)
            bufA[et][ks] = *(const short8*)(whb + (size_t)(et * 64 + ks) * 512);

    unsigned int mw = mrow[0];
    float4 fv = *(const float4*)f2p;

    for (int mb = 0; mb < 32; mb += 2) {
        // ===== even block mb: produce->ptile[0], compute with bufA =====
        {
            float fvv[4] = {fv.x, fv.y, fv.z, fv.w};
            unsigned int mloc = mw >> cshift;
            float pv[4];
#pragma unroll
            for (int j = 0; j < 4; j++) {
                float t_ = f1n + fvv[j];
                float e_ = fmaxf(t_, 0.2f * t_);               // leaky relu
                pv[j] = ((mloc >> j) & 1u) ? exp2f(e_) : 0.f;
            }
            unsigned int r0 = cvtpk(pv[0], pv[1]);
            unsigned int r1 = cvtpk(pv[2], pv[3]);
            den += (blo(r0) + bhi(r0)) + (blo(r1) + bhi(r1));
            uint2 pr; pr.x = r0; pr.y = r1;
            *(uint2*)&ptile[0][wrg][l31][cshift] = pr;
            // prefetch mask/f2 for block mb+1 (always exists: mb+1 <= 31)
            mw = mrow[(size_t)(mb + 1) * 1024];
            fv = *(const float4*)(f2p + (mb + 1) * 32);
            __syncthreads();
            short8 af0 = *(const short8*)&ptile[0][wrg][l31][l5 * 8];
            short8 af1 = *(const short8*)&ptile[0][wrg][l31][16 + l5 * 8];
            // prefetch WhF frags for block mb+1 into bufB
            int m16n = (mb + 1) * 2;
#pragma unroll
            for (int et = 0; et < 2; et++)
#pragma unroll
                for (int ks = 0; ks < 2; ks++)
                    bufB[et][ks] =
                        *(const short8*)(whb + (size_t)(et * 64 + m16n + ks) * 512);
            __builtin_amdgcn_s_setprio(1);
#pragma unroll
            for (int et = 0; et < 2; et++) {
                acc[et] = __builtin_amdgcn_mfma_f32_32x32x16_bf16(
                    af0, bufA[et][0], acc[et], 0, 0, 0);
                acc[et] = __builtin_amdgcn_mfma_f32_32x32x16_bf16(
                    af1, bufA[et][1], acc[et], 0, 0, 0);
            }
            __builtin_amdgcn_s_setprio(0);
        }
        // ===== odd block mb+1: produce->ptile[1], compute with bufB =====
        {
            float fvv[4] = {fv.x, fv.y, fv.z, fv.w};
            unsigned int mloc = mw >> cshift;
            float pv[4];
#pragma unroll
            for (int j = 0; j < 4; j++) {
                float t_ = f1n + fvv[j];
                float e_ = fmaxf(t_, 0.2f * t_);               // leaky relu
                pv[j] = ((mloc >> j) & 1u) ? exp2f(e_) : 0.f;
            }
            unsigned int r0 = cvtpk(pv[0], pv[1]);
            unsigned int r1 = cvtpk(pv[2], pv[3]);
            den += (blo(r0) + bhi(r0)) + (blo(r1) + bhi(r1));
            uint2 pr; pr.x = r0; pr.y = r1;
            *(uint2*)&ptile[1][wrg][l31][cshift] = pr;
            // prefetch mask/f2 for block mb+2 (if any)
            if (mb < 30) {
                mw = mrow[(size_t)(mb + 2) * 1024];
                fv = *(const float4*)(f2p + (mb + 2) * 32);
            }
            __syncthreads();
            short8 af0 = *(const short8*)&ptile[1][wrg][l31][l5 * 8];
            short8 af1 = *(const short8*)&ptile[1][wrg][l31][16 + l5 * 8];
            if (mb < 30) {                      // prefetch frags for mb+2
                int m16n = (mb + 2) * 2;
#pragma unroll
                for (int et = 0; et < 2; et++)
#pragma unroll
                    for (int ks = 0; ks < 2; ks++)
                        bufA[et][ks] =
                            *(const short8*)(whb + (size_t)(et * 64 + m16n + ks) * 512);
            }
            __builtin_amdgcn_s_setprio(1);
#pragma unroll
            for (int et = 0; et < 2; et++) {
                acc[et] = __builtin_amdgcn_mfma_f32_32x32x16_bf16(
                    af0, bufB[et][0], acc[et], 0, 0, 0);
                acc[et] = __builtin_amdgcn_mfma_f32_32x32x16_bf16(
                    af1, bufB[et][1], acc[et], 0, 0, 0);
            }
            __builtin_amdgcn_s_setprio(0);
        }
    }

    // den: lane has rows l31, cols cshift..+3; fold l5 halves, then 4 q-waves.
    den += __shfl_xor(den, 32, 64);
    if (l5 == 0) dred[wrg][q][l31] = den;
    __syncthreads();
    float denf = dred[wrg][0][l31] + dred[wrg][1][l31]
               + dred[wrg][2][l31] + dred[wrg][3][l31];

#pragma unroll
    for (int reg = 0; reg < 16; reg++) {
        int r = (reg & 3) + 8 * (reg >> 2) + 4 * l5;   // C-layout row (0..31)
        float dr = __shfl(denf, r, 64);
        float rdr = 1.0f / dr;
        int nn = n0 + r;
#pragma unroll
        for (int et = 0; et < 2; et++) {
            int e = q * 64 + et * 32 + l31;
            float v = acc[et][reg] * rdr;
            float o = v > 0.f ? v : __expf(v) - 1.f;   // elu
            feat[(size_t)(b * 1024 + nn) * 1024 + h * 256 + e] = f2b(o);
        }
    }
}

// K3: out = feat @ W_act + b_act  (M=8192, K=1024, N=64), out dtype per flag.
// Static-array double-buffer (a0/a1/b0/b1 named, hand-unrolled 2x).
__global__ __launch_bounds__(256) void k3_out(
        const unsigned short* __restrict__ feat,
        const unsigned short* __restrict__ WactT,   // [64][1024]
        const unsigned short* __restrict__ bact,
        void* __restrict__ out, const int* __restrict__ flag) {
    __shared__ unsigned short sa0[2 * 512], sa1[2 * 512];
    __shared__ unsigned short sb0[4 * 512], sb1[4 * 512];
    int tid = threadIdx.x;
    int w = tid >> 6, lane = tid & 63;
    int lr = lane & 15, lq = lane >> 4;
    int row0 = blockIdx.x * 32;
    int g = w & 1, ch = w >> 1;
    int bf16out = *flag;
    f32x4 acc[2] = {};

    auto stage = [&](unsigned short* dA, unsigned short* dB, int k0) {
        if (w < 2) {
            const unsigned short* src =
                feat + (size_t)(row0 + w * 16 + lr) * 1024 + k0 + lq * 8;
            glds16(src, dA + w * 512);
        } else {
#pragma unroll
            for (int s = 0; s < 2; s++) {
                int t = (w - 2) * 2 + s;
                const unsigned short* src =
                    WactT + (size_t)(t * 16 + lr) * 1024 + k0 + lq * 8;
                glds16(src, dB + t * 512);
            }
        }
    };
    auto compute = [&](const unsigned short* sA, const unsigned short* sB) {
        short8 af = *(const short8*)&sA[g * 512 + lane * 8];
#pragma unroll
        for (int j = 0; j < 2; j++) {
            short8 bf = *(const short8*)&sB[(ch * 2 + j) * 512 + lane * 8];
            acc[j] = __builtin_amdgcn_mfma_f32_16x16x32_bf16(af, bf, acc[j], 0, 0, 0);
        }
    };

    stage(sa0, sb0, 0);
    __syncthreads();
    for (int t = 0; t < 32; t += 2) {
        stage(sa1, sb1, (t + 1) * 32);          // t+1 <= 31 always
        compute(sa0, sb0);
        __syncthreads();
        if (t + 2 < 32) stage(sa0, sb0, (t + 2) * 32);
        compute(sa1, sb1);
        __syncthreads();
    }
#pragma unroll
    for (int j = 0; j < 2; j++) {
        int col = ch * 32 + j * 16 + lr;
        float bv = b2f(bact[col]);
#pragma unroll
        for (int rr = 0; rr < 4; rr++) {
            int r = row0 + g * 16 + lq * 4 + rr;
            float val = acc[j][rr] + bv;
            if (bf16out) ((unsigned short*)out)[(size_t)r * 64 + col] = f2b(val);
            else         ((float*)out)[(size_t)r * 64 + col] = val;
        }
    }
}

extern "C" void kernel_launch(void* const* d_in, const int* in_sizes, int n_in,
                              void* d_out, int out_size, void* d_ws, size_t ws_size,
                              hipStream_t stream) {
    const void* x    = d_in[0];
    const int*  adj  = (const int*)d_in[1];
    const void* W    = d_in[2];
    const void* a1   = d_in[3];
    const void* a2   = d_in[4];
    const void* Wact = d_in[5];
    const void* bact = d_in[6];

    char* ws = (char*)d_ws;
    unsigned short* WhF   = (unsigned short*)(ws);               // 16 MB  frag-tile
    unsigned short* xb    = (unsigned short*)(ws + 16777216);    // 16 MB  (== feat)
    unsigned short* feat  = (unsigned short*)(ws + 16777216);    // 16 MB  [8192][1024]
    unsigned short* WT    = (unsigned short*)(ws + 33554432);    //  2 MB  [4][256][1024]
    unsigned short* WactT = (unsigned short*)(ws + 35651584);    // 128 KB [64][1024]
    float*          f1    = (float*)(ws + 35782656);             // 128 KB [32][1024]
    float*          f2    = (float*)(ws + 35913728);             // 128 KB [32][1024]
    unsigned short* a1b   = (unsigned short*)(ws + 36044800);    // 2 KB
    unsigned short* a2b   = (unsigned short*)(ws + 36046848);    // 2 KB
    unsigned short* bactb = (unsigned short*)(ws + 36048896);    // 128 B
    int*            flag  = (int*)(ws + 36049024);               // 16 B
    unsigned int*   maskT = (unsigned int*)(ws + 36700160);      //  1 MB (own slot,
                                                                 //  no WT alias)
    if (ws_size < (size_t)37748736) return;

    prep_all<<<4561, 256, 0, stream>>>((const unsigned int*)x, x, W, Wact,
                                       a1, a2, bact, adj, xb, WT, WactT,
                                       a1b, a2b, bactb, flag, (float4*)f1,
                                       maskT);
    k1_gemm<<<dim3(8, 64), 256, 0, stream>>>(xb, WT, WhF, a1b, a2b, f1, f2);
    k2_attn<<<512, 512, 0, stream>>>(WhF, maskT, f1, f2, feat);
    k3_out<<<256, 256, 0, stream>>>(feat, WactT, bactb, d_out, flag);
}

// Round 9
// 201.362 us; speedup vs baseline: 1.4872x; 1.4872x over previous
//
#include <hip/hip_runtime.h>
#include <stdint.h>

// Problem constants: B=8, N=1024, IN_F=1024, E=256, H=4, A=64
typedef __attribute__((ext_vector_type(8))) short short8;
typedef __attribute__((ext_vector_type(4))) float f32x4;
typedef __attribute__((ext_vector_type(16))) float f32x16;

// WhF frag-tile layout (32x32 MFMA-B order; k1 epilogue -> k2):
//   element (hb, e, m): et=e>>5, e31=e&31, m16=m>>4, l5=(m>>3)&1, m7=m&7
//   u16 idx = ((hb*8+et)*64 + m16)*512 + (l5*32+e31)*8 + m7
// => one (et,m16) tile is 1KB contiguous in lane order (lane=l5*32+e31).
//
// r8 LESSON (do not re-attempt): fusing pack_adj into prep_all as 128 tail
// blocks serialized the 8M ballots (0.5 blocks/CU, ~500-900cy load latency
// fully exposed) -> prep 10us -> 130us. The 32768-block standalone kernel's
// TLP is what makes pack_adj cheap. Launch-fusion must preserve parallelism.

__device__ __forceinline__ float b2f(unsigned short u) {
    union { unsigned int i; float f; } v; v.i = ((unsigned int)u) << 16; return v.f;
}
__device__ __forceinline__ unsigned short f2b(float f) {
    union { float f; unsigned int i; } v; v.f = f;
    unsigned int u = v.i;
    u = (u + 0x7FFFu + ((u >> 16) & 1u)) >> 16;
    return (unsigned short)u;
}
// packed bf16 pair: lo=rne(a), hi=rne(b) — 1 instr replaces 2x f2b + pack
__device__ __forceinline__ unsigned int cvtpk(float a, float b) {
    unsigned int r;
    asm("v_cvt_pk_bf16_f32 %0, %1, %2" : "=v"(r) : "v"(a), "v"(b));
    return r;
}
__device__ __forceinline__ float blo(unsigned int u) {
    union { unsigned int i; float f; } v; v.i = u << 16; return v.f;
}
__device__ __forceinline__ float bhi(unsigned int u) {
    union { unsigned int i; float f; } v; v.i = u & 0xFFFF0000u; return v.f;
}
__device__ __forceinline__ void glds16(const void* g, const void* l) {
    __builtin_amdgcn_global_load_lds(
        (const __attribute__((address_space(1))) unsigned int*)g,
        (__attribute__((address_space(3))) unsigned int*)l, 16, 0, 0);
}

__device__ __forceinline__ void cvt8(const void* in, unsigned short* out,
                                     int f, int grp) {
    if (f) {
        ((ushort4*)out)[grp * 2]     = ((const ushort4*)in)[grp * 2];
        ((ushort4*)out)[grp * 2 + 1] = ((const ushort4*)in)[grp * 2 + 1];
    } else {
        const float4* p = (const float4*)in + (size_t)grp * 2;
        float4 a = p[0], b = p[1];
        ushort4 o0, o1;
        o0.x = f2b(a.x); o0.y = f2b(a.y); o0.z = f2b(a.z); o0.w = f2b(a.w);
        o1.x = f2b(b.x); o1.y = f2b(b.y); o1.z = f2b(b.z); o1.w = f2b(b.w);
        ((ushort4*)out)[grp * 2]     = o0;
        ((ushort4*)out)[grp * 2 + 1] = o1;
    }
}

// prep_all: single launch replacing prep+conv8+t2+zero.
// Blocks: [0,4096) x-convert | [4096,4352) W transpose | [4352,4416) zero f1/f2
//         | 4416 smalls+flag | [4417,4433) W_act transpose (1024x64 -> 64x1024).
// Each block re-derives the dtype flag from x[0:64] (256B, L2-hot).
__global__ __launch_bounds__(256) void prep_all(
        const unsigned int* __restrict__ x4,
        const void* __restrict__ x, const void* __restrict__ W,
        const void* __restrict__ Wact,
        const void* __restrict__ a1, const void* __restrict__ a2,
        const void* __restrict__ bact,
        unsigned short* __restrict__ xb, unsigned short* __restrict__ WT,
        unsigned short* __restrict__ WactT,
        unsigned short* __restrict__ a1b, unsigned short* __restrict__ a2b,
        unsigned short* __restrict__ bactb,
        int* __restrict__ flag, float4* __restrict__ fz) {
    __shared__ unsigned int tile[64 * 65];
    __shared__ int sflag;
    int tid = threadIdx.x;
    int bid = blockIdx.x;
    if (bid >= 4352 && bid < 4416) {                  // zero f1/f2 (256 KB)
        fz[(bid - 4352) * 256 + tid] = float4{0.f, 0.f, 0.f, 0.f};
        return;
    }
    if (tid < 64) {                                   // per-block dtype detect
        unsigned int wv = x4[tid];
        unsigned int e = (wv >> 7) & 0xFF;
        unsigned long long m = __ballot(e >= 100 && e <= 140);
        if (tid == 0) sflag = (__popcll(m) >= 48) ? 1 : 0;
    }
    __syncthreads();
    int f = sflag;

    if (bid < 4096) {                                 // x -> xb bf16
        cvt8(x, xb, f, bid * 256 + tid);
        return;
    }
    if (bid == 4416) {                                // smalls + flag publish
        if (tid == 0) flag[0] = f;
        if (tid < 128) cvt8(a1, a1b, f, tid);
        else           cvt8(a2, a2b, f, tid - 128);
        if (tid < 8)   cvt8(bact, bactb, f, tid);
        return;
    }
    // LDS-tiled transpose: W (256 blocks, C=256) or W_act (16 blocks, C=64).
    const void* in; unsigned short* out; int C, bt, c0, r0;
    if (bid < 4352) {
        int lb = bid - 4096;
        in = W; out = WT; C = 256;
        c0 = (lb & 3) * 64;
        r0 = ((lb >> 2) & 15) * 64;
        bt = lb >> 6;
    } else {
        int lb = bid - 4417;
        in = Wact; out = WactT; C = 64;
        c0 = 0; r0 = lb * 64; bt = 0;
    }
    int rl = tid >> 2;
    int cc = (tid & 3) * 16;
    size_t ibase = ((size_t)bt * 1024 + (r0 + rl)) * C + c0 + cc;
    unsigned short v[16];
    if (f) {
        const unsigned short* p = (const unsigned short*)in + ibase;
        short8 a = *(const short8*)p;
        short8 b = *(const short8*)(p + 8);
#pragma unroll
        for (int j = 0; j < 8; j++) { v[j] = (unsigned short)a[j]; v[8 + j] = (unsigned short)b[j]; }
    } else {
        const float* p = (const float*)in + ibase;
#pragma unroll
        for (int j = 0; j < 16; j++) v[j] = f2b(p[j]);
    }
#pragma unroll
    for (int j = 0; j < 16; j++)
        tile[(cc + j) * 65 + rl] = v[j];
    __syncthreads();
    int cl = tid >> 2;
    int rch = (tid & 3) * 16;
    unsigned short o[16];
#pragma unroll
    for (int j = 0; j < 16; j++)
        o[j] = (unsigned short)tile[cl * 65 + rch + j];
    unsigned short* op = out + ((size_t)bt * C + (c0 + cl)) * 1024 + r0 + rch;
#pragma unroll
    for (int q = 0; q < 4; q++) {
        ushort4 s; s.x = o[q*4]; s.y = o[q*4+1]; s.z = o[q*4+2]; s.w = o[q*4+3];
        ((ushort4*)op)[q] = s;
    }
}

// Pack adj into TRANSPOSED bitmask maskT[b][mword=m>>5][n] (u32), via ballot.
// KEEP as a standalone 32768-block launch: that block count is the TLP that
// hides the load latency (r8: fused 128-block version was ~100us slower).
__global__ void pack_adj(const int* __restrict__ adj,
                         unsigned int* __restrict__ maskT) {
    int gid = blockIdx.x * 256 + threadIdx.x;
    int lane = threadIdx.x & 63;
    unsigned long long m = __ballot(adj[gid] > 0);
    if (lane == 0) {
        int lin = gid >> 6;           // (b*1024+n)*16 + m0/64
        int mw = (lin & 15) * 2;
        int bn = lin >> 4;
        int b = bn >> 10, n = bn & 1023;
        maskT[(size_t)(b * 32 + mw) * 1024 + n]     = (unsigned int)m;
        maskT[(size_t)(b * 32 + mw + 1) * 1024 + n] = (unsigned int)(m >> 32);
    }
}

// K1: Wh = x @ W[h] -> WhF frag-tile bf16 (32x32 layout). Epilogue also
// accumulates f1 = Wh.a1, f2 = Wh.a2 (pre-scaled by log2e) via shfl+atomics.
// Config = r3 best (128x128 tile, BK=64, grid dim3(8,64), XCD swizzle:
// FETCH 16.6MB verified). Static-array double-buffer (r7: 43->41us).
// CLOSED at ~41us: runs 420 TF, ABOVE the m97-structure small-problem
// reference curve (m102: 320 TF @ 16 GFLOP); further gains need the 256^2
// 8-phase schedule, which at this M,N gives only 0.5 blocks/CU. Do not
// re-attempt within-block pipelining (r4) or smaller tiles (r5).
__global__ __launch_bounds__(256) void k1_gemm(
        const unsigned short* __restrict__ x,
        const unsigned short* __restrict__ WT,      // [H][E=256][K=1024]
        unsigned short* __restrict__ WhF,
        const unsigned short* __restrict__ a1b,
        const unsigned short* __restrict__ a2b,
        float* __restrict__ f1, float* __restrict__ f2) {
    __shared__ unsigned short smA0[16 * 512];       // 16KB each
    __shared__ unsigned short smA1[16 * 512];
    __shared__ unsigned short smB0[16 * 512];
    __shared__ unsigned short smB1[16 * 512];
    int tid = threadIdx.x;
    int w = tid >> 6, lane = tid & 63;
    int lr = lane & 15, lq = lane >> 4;
    int lin = blockIdx.x + 8 * blockIdx.y;      // HW dispatch-linear id
    int xcd = lin & 7, kk = lin >> 3;
    int ct = kk >> 3;                           // col tile 0..7 (h, e-half)
    int rt = xcd * 8 + (kk & 7);                // row tile 0..63 (b = xcd)
    int col0 = ct * 128;
    int row0 = rt * 128;
    int h = col0 >> 8;
    int e_base = col0 & 255;
    int b = row0 >> 10;
    int m_base = row0 & 1023;
    int wr = w >> 1, wc = w & 1;

    f32x4 acc[4][4] = {};

    // stage one BK=64 tile pair (16KB A + 16KB B); 8 glds16 per thread
    auto stage = [&](unsigned short* dA, unsigned short* dB, int k0) {
#pragma unroll
        for (int s = 0; s < 4; s++) {
            int g = 4 * w + s;                  // g = kh*8 + rb
            int rb = g & 7, kh = g >> 3;
            const unsigned short* srcA =
                x + (size_t)(row0 + rb * 16 + lr) * 1024 + k0 + kh * 32 + lq * 8;
            glds16(srcA, dA + g * 512);
            const unsigned short* srcB =
                WT + (size_t)(h * 256 + e_base + rb * 16 + lr) * 1024
                   + k0 + kh * 32 + lq * 8;
            glds16(srcB, dB + g * 512);
        }
    };
    auto compute = [&](const unsigned short* sA, const unsigned short* sB) {
#pragma unroll
        for (int kh = 0; kh < 2; kh++) {
            short8 af[4], bf[4];
#pragma unroll
            for (int i = 0; i < 4; i++)
                af[i] = *(const short8*)&sA[(kh * 8 + wr * 4 + i) * 512 + lane * 8];
#pragma unroll
            for (int j = 0; j < 4; j++)
                bf[j] = *(const short8*)&sB[(kh * 8 + wc * 4 + j) * 512 + lane * 8];
#pragma unroll
            for (int i = 0; i < 4; i++)
#pragma unroll
                for (int j = 0; j < 4; j++)
                    acc[i][j] = __builtin_amdgcn_mfma_f32_16x16x32_bf16(
                        af[i], bf[j], acc[i][j], 0, 0, 0);
        }
    };

    stage(smA0, smB0, 0);
    __syncthreads();                            // buf0 ready
    for (int t = 0; t < 16; t += 2) {
        stage(smA1, smB1, (t + 1) * 64);        // t+1 <= 15 always
        compute(smA0, smB0);
        __syncthreads();                        // drain buf1 loads + LDS sync
        if (t + 2 < 16) stage(smA0, smB0, (t + 2) * 64);
        compute(smA1, smB1);
        __syncthreads();
    }

    // Epilogue 1: WhF frag-tile stores (32x32 layout).
    int hb = h * 8 + b;
#pragma unroll
    for (int i = 0; i < 4; i++) {
#pragma unroll
        for (int j = 0; j < 4; j++) {
            int e = e_base + (wc * 4 + j) * 16 + lr;
            int et = e >> 5, e31 = e & 31;
            int m16 = (m_base >> 4) + wr * 4 + i;
            ushort4 vs;
            vs.x = f2b(acc[i][j][0]);
            vs.y = f2b(acc[i][j][1]);
            vs.z = f2b(acc[i][j][2]);
            vs.w = f2b(acc[i][j][3]);
            size_t idx = ((size_t)((hb * 8 + et) * 64 + m16) * 512)
                         + ((lq >> 1) * 32 + e31) * 8 + (lq & 1) * 4;
            *(ushort4*)&WhF[idx] = vs;
        }
    }

    // Epilogue 2: f1/f2 partials via shfl-reduce over the 16-lane e-groups.
    const float LOG2E = 1.44269504f;
    float a1v[4], a2v[4];
#pragma unroll
    for (int j = 0; j < 4; j++) {
        int e = e_base + (wc * 4 + j) * 16 + lr;
        a1v[j] = b2f(a1b[h * 256 + e]);
        a2v[j] = b2f(a2b[h * 256 + e]);
    }
#pragma unroll
    for (int i = 0; i < 4; i++) {
#pragma unroll
        for (int reg = 0; reg < 4; reg++) {
            float s1 = 0.f, s2 = 0.f;
#pragma unroll
            for (int j = 0; j < 4; j++) {
                s1 += acc[i][j][reg] * a1v[j];
                s2 += acc[i][j][reg] * a2v[j];
            }
            s1 += __shfl_xor(s1, 1, 64); s2 += __shfl_xor(s2, 1, 64);
            s1 += __shfl_xor(s1, 2, 64); s2 += __shfl_xor(s2, 2, 64);
            s1 += __shfl_xor(s1, 4, 64); s2 += __shfl_xor(s2, 4, 64);
            s1 += __shfl_xor(s1, 8, 64); s2 += __shfl_xor(s2, 8, 64);
            if (lr == 0) {
                int m = m_base + (wr * 4 + i) * 16 + lq * 4 + reg;
                atomicAdd(&f1[hb * 1024 + m], s1 * LOG2E);
                atomicAdd(&f2[hb * 1024 + m], s2 * LOG2E);
            }
        }
    }
}

// K2: masked-softmax attention + P@Wh + ELU -> feat bf16.
// Block = 512 thr = 8 waves = 2 row-groups (64 rows) x 4 e-quarter waves.
// The 4 q-waves of a row-group SPLIT the 32 softmax columns (4 p/lane/iter)
// and exchange the bf16 P-tile through a double-buffered LDS tile. cvt_pk
// packs p-pairs in one instr; den accumulates the ROUNDED p halves.
// m-loop HAND-UNROLLED 2x (named bufA/bufB, literal ptile idx — rule #20).
// s_setprio(1/0) around MFMA clusters (T5: produce/consume wave role-split).
__global__ __launch_bounds__(512, 4) void k2_attn(
        const unsigned short* __restrict__ WhF,
        const unsigned int* __restrict__ maskT,     // [8][32][1024]
        const float* __restrict__ f1, const float* __restrict__ f2,
        unsigned short* __restrict__ feat) {
    __shared__ unsigned short ptile[2][2][32][40];  // [buf][rg][row][col pad40]
    __shared__ float dred[2][4][32];                // [rg][q][row]
    int tid = threadIdx.x;
    int w = tid >> 6, lane = tid & 63;
    int q = w & 3, wrg = w >> 2;
    int l5 = lane >> 5, l31 = lane & 31;
    int bid = blockIdx.x;
    int xcd = bid & 7, idx = bid >> 3;          // idx 0..63
    int hb = xcd + 8 * (idx >> 4);              // 4 hb per XCD, same b = xcd
    int rgb = idx & 15;                         // 16 row-blocks of 64
    int n0 = rgb * 64 + wrg * 32;
    int h = hb >> 3, b = hb & 7;
    int row = n0 + l31;
    float f1n = f1[hb * 1024 + row];            // already *log2e
    const unsigned short* whb = WhF + (size_t)(hb * 8 + q * 2) * 64 * 512
                                + lane * 8;
    const unsigned int* mrow = maskT + (size_t)b * 32 * 1024 + row;
    const float* f2p = f2 + hb * 1024 + q * 8 + l5 * 4;   // this lane's 4 cols
    int cshift = q * 8 + l5 * 4;                // col base within 32-block

    f32x16 acc[2] = {};                         // e = q*64 + et*32 + l31
    float den = 0.f;

    short8 bufA[2][2], bufB[2][2];              // [et][ks] — named, static idx
#pragma unroll
    for (int et = 0; et < 2; et++)
#pragma unroll
        for (int ks = 0; ks < 2; ks++)
            bufA[et][ks] = *(const short8*)(whb + (size_t)(et * 64 + ks) * 512);

    unsigned int mw = mrow[0];
    float4 fv = *(const float4*)f2p;

    for (int mb = 0; mb < 32; mb += 2) {
        // ===== even block mb: produce->ptile[0], compute with bufA =====
        {
            float fvv[4] = {fv.x, fv.y, fv.z, fv.w};
            unsigned int mloc = mw >> cshift;
            float pv[4];
#pragma unroll
            for (int j = 0; j < 4; j++) {
                float t_ = f1n + fvv[j];
                float e_ = fmaxf(t_, 0.2f * t_);               // leaky relu
                pv[j] = ((mloc >> j) & 1u) ? exp2f(e_) : 0.f;
            }
            unsigned int r0 = cvtpk(pv[0], pv[1]);
            unsigned int r1 = cvtpk(pv[2], pv[3]);
            den += (blo(r0) + bhi(r0)) + (blo(r1) + bhi(r1));
            uint2 pr; pr.x = r0; pr.y = r1;
            *(uint2*)&ptile[0][wrg][l31][cshift] = pr;
            // prefetch mask/f2 for block mb+1 (always exists: mb+1 <= 31)
            mw = mrow[(size_t)(mb + 1) * 1024];
            fv = *(const float4*)(f2p + (mb + 1) * 32);
            __syncthreads();
            short8 af0 = *(const short8*)&ptile[0][wrg][l31][l5 * 8];
            short8 af1 = *(const short8*)&ptile[0][wrg][l31][16 + l5 * 8];
            // prefetch WhF frags for block mb+1 into bufB
            int m16n = (mb + 1) * 2;
#pragma unroll
            for (int et = 0; et < 2; et++)
#pragma unroll
                for (int ks = 0; ks < 2; ks++)
                    bufB[et][ks] =
                        *(const short8*)(whb + (size_t)(et * 64 + m16n + ks) * 512);
            __builtin_amdgcn_s_setprio(1);
#pragma unroll
            for (int et = 0; et < 2; et++) {
                acc[et] = __builtin_amdgcn_mfma_f32_32x32x16_bf16(
                    af0, bufA[et][0], acc[et], 0, 0, 0);
                acc[et] = __builtin_amdgcn_mfma_f32_32x32x16_bf16(
                    af1, bufA[et][1], acc[et], 0, 0, 0);
            }
            __builtin_amdgcn_s_setprio(0);
        }
        // ===== odd block mb+1: produce->ptile[1], compute with bufB =====
        {
            float fvv[4] = {fv.x, fv.y, fv.z, fv.w};
            unsigned int mloc = mw >> cshift;
            float pv[4];
#pragma unroll
            for (int j = 0; j < 4; j++) {
                float t_ = f1n + fvv[j];
                float e_ = fmaxf(t_, 0.2f * t_);               // leaky relu
                pv[j] = ((mloc >> j) & 1u) ? exp2f(e_) : 0.f;
            }
            unsigned int r0 = cvtpk(pv[0], pv[1]);
            unsigned int r1 = cvtpk(pv[2], pv[3]);
            den += (blo(r0) + bhi(r0)) + (blo(r1) + bhi(r1));
            uint2 pr; pr.x = r0; pr.y = r1;
            *(uint2*)&ptile[1][wrg][l31][cshift] = pr;
            // prefetch mask/f2 for block mb+2 (if any)
            if (mb < 30) {
                mw = mrow[(size_t)(mb + 2) * 1024];
                fv = *(const float4*)(f2p + (mb + 2) * 32);
            }
            __syncthreads();
            short8 af0 = *(const short8*)&ptile[1][wrg][l31][l5 * 8];
            short8 af1 = *(const short8*)&ptile[1][wrg][l31][16 + l5 * 8];
            if (mb < 30) {                      // prefetch frags for mb+2
                int m16n = (mb + 2) * 2;
#pragma unroll
                for (int et = 0; et < 2; et++)
#pragma unroll
                    for (int ks = 0; ks < 2; ks++)
                        bufA[et][ks] =
                            *(const short8*)(whb + (size_t)(et * 64 + m16n + ks) * 512);
            }
            __builtin_amdgcn_s_setprio(1);
#pragma unroll
            for (int et = 0; et < 2; et++) {
                acc[et] = __builtin_amdgcn_mfma_f32_32x32x16_bf16(
                    af0, bufB[et][0], acc[et], 0, 0, 0);
                acc[et] = __builtin_amdgcn_mfma_f32_32x32x16_bf16(
                    af1, bufB[et][1], acc[et], 0, 0, 0);
            }
            __builtin_amdgcn_s_setprio(0);
        }
    }

    // den: lane has rows l31, cols cshift..+3; fold l5 halves, then 4 q-waves.
    den += __shfl_xor(den, 32, 64);
    if (l5 == 0) dred[wrg][q][l31] = den;
    __syncthreads();
    float denf = dred[wrg][0][l31] + dred[wrg][1][l31]
               + dred[wrg][2][l31] + dred[wrg][3][l31];

#pragma unroll
    for (int reg = 0; reg < 16; reg++) {
        int r = (reg & 3) + 8 * (reg >> 2) + 4 * l5;   // C-layout row (0..31)
        float dr = __shfl(denf, r, 64);
        float rdr = 1.0f / dr;
        int nn = n0 + r;
#pragma unroll
        for (int et = 0; et < 2; et++) {
            int e = q * 64 + et * 32 + l31;
            float v = acc[et][reg] * rdr;
            float o = v > 0.f ? v : __expf(v) - 1.f;   // elu
            feat[(size_t)(b * 1024 + nn) * 1024 + h * 256 + e] = f2b(o);
        }
    }
}

// K3: out = feat @ W_act + b_act  (M=8192, K=1024, N=64), out dtype per flag.
// Static-array double-buffer (a0/a1/b0/b1 named, hand-unrolled 2x).
__global__ __launch_bounds__(256) void k3_out(
        const unsigned short* __restrict__ feat,
        const unsigned short* __restrict__ WactT,   // [64][1024]
        const unsigned short* __restrict__ bact,
        void* __restrict__ out, const int* __restrict__ flag) {
    __shared__ unsigned short sa0[2 * 512], sa1[2 * 512];
    __shared__ unsigned short sb0[4 * 512], sb1[4 * 512];
    int tid = threadIdx.x;
    int w = tid >> 6, lane = tid & 63;
    int lr = lane & 15, lq = lane >> 4;
    int row0 = blockIdx.x * 32;
    int g = w & 1, ch = w >> 1;
    int bf16out = *flag;
    f32x4 acc[2] = {};

    auto stage = [&](unsigned short* dA, unsigned short* dB, int k0) {
        if (w < 2) {
            const unsigned short* src =
                feat + (size_t)(row0 + w * 16 + lr) * 1024 + k0 + lq * 8;
            glds16(src, dA + w * 512);
        } else {
#pragma unroll
            for (int s = 0; s < 2; s++) {
                int t = (w - 2) * 2 + s;
                const unsigned short* src =
                    WactT + (size_t)(t * 16 + lr) * 1024 + k0 + lq * 8;
                glds16(src, dB + t * 512);
            }
        }
    };
    auto compute = [&](const unsigned short* sA, const unsigned short* sB) {
        short8 af = *(const short8*)&sA[g * 512 + lane * 8];
#pragma unroll
        for (int j = 0; j < 2; j++) {
            short8 bf = *(const short8*)&sB[(ch * 2 + j) * 512 + lane * 8];
            acc[j] = __builtin_amdgcn_mfma_f32_16x16x32_bf16(af, bf, acc[j], 0, 0, 0);
        }
    };

    stage(sa0, sb0, 0);
    __syncthreads();
    for (int t = 0; t < 32; t += 2) {
        stage(sa1, sb1, (t + 1) * 32);          // t+1 <= 31 always
        compute(sa0, sb0);
        __syncthreads();
        if (t + 2 < 32) stage(sa0, sb0, (t + 2) * 32);
        compute(sa1, sb1);
        __syncthreads();
    }
#pragma unroll
    for (int j = 0; j < 2; j++) {
        int col = ch * 32 + j * 16 + lr;
        float bv = b2f(bact[col]);
#pragma unroll
        for (int rr = 0; rr < 4; rr++) {
            int r = row0 + g * 16 + lq * 4 + rr;
            float val = acc[j][rr] + bv;
            if (bf16out) ((unsigned short*)out)[(size_t)r * 64 + col] = f2b(val);
            else         ((float*)out)[(size_t)r * 64 + col] = val;
        }
    }
}

extern "C" void kernel_launch(void* const* d_in, const int* in_sizes, int n_in,
                              void* d_out, int out_size, void* d_ws, size_t ws_size,
                              hipStream_t stream) {
    const void* x    = d_in[0];
    const int*  adj  = (const int*)d_in[1];
    const void* W    = d_in[2];
    const void* a1   = d_in[3];
    const void* a2   = d_in[4];
    const void* Wact = d_in[5];
    const void* bact = d_in[6];

    char* ws = (char*)d_ws;
    unsigned short* WhF   = (unsigned short*)(ws);               // 16 MB  frag-tile
    unsigned short* xb    = (unsigned short*)(ws + 16777216);    // 16 MB  (== feat)
    unsigned short* feat  = (unsigned short*)(ws + 16777216);    // 16 MB  [8192][1024]
    unsigned short* WT    = (unsigned short*)(ws + 33554432);    //  2 MB  [4][256][1024]
    unsigned int*   maskT = (unsigned int*)(ws + 33554432);      //  1 MB  (== WT, after k1)
    unsigned short* WactT = (unsigned short*)(ws + 35651584);    // 128 KB [64][1024]
    float*          f1    = (float*)(ws + 35782656);             // 128 KB [32][1024]
    float*          f2    = (float*)(ws + 35913728);             // 128 KB [32][1024]
    unsigned short* a1b   = (unsigned short*)(ws + 36044800);    // 2 KB
    unsigned short* a2b   = (unsigned short*)(ws + 36046848);    // 2 KB
    unsigned short* bactb = (unsigned short*)(ws + 36048896);    // 128 B
    int*            flag  = (int*)(ws + 36049024);               // 16 B
    if (ws_size < (size_t)36049040) return;

    prep_all<<<4433, 256, 0, stream>>>((const unsigned int*)x, x, W, Wact,
                                       a1, a2, bact, xb, WT, WactT,
                                       a1b, a2b, bactb, flag, (float4*)f1);
    k1_gemm<<<dim3(8, 64), 256, 0, stream>>>(xb, WT, WhF, a1b, a2b, f1, f2);
    pack_adj<<<32768, 256, 0, stream>>>(adj, maskT);   // overwrites WT (dead)
    k2_attn<<<512, 512, 0, stream>>>(WhF, maskT, f1, f2, feat);
    k3_out<<<256, 256, 0, stream>>>(feat, WactT, bactb, d_out, flag);
}

// Round 10
// 196.966 us; speedup vs baseline: 1.5204x; 1.0223x over previous
//
#include <hip/hip_runtime.h>
#include <stdint.h>

// Problem constants: B=8, N=1024, IN_F=1024, E=256, H=4, A=64
typedef __attribute__((ext_vector_type(8))) short short8;
typedef __attribute__((ext_vector_type(4))) float f32x4;
typedef __attribute__((ext_vector_type(16))) float f32x16;

// WhF frag-tile layout (32x32 MFMA-B order; k1 epilogue -> k2):
//   element (hb, e, m): et=e>>5, e31=e&31, m16=m>>4, l5=(m>>3)&1, m7=m&7
//   u16 idx = ((hb*8+et)*64 + m16)*512 + (l5*32+e31)*8 + m7
// => one (et,m16) tile is 1KB contiguous in lane order (lane=l5*32+e31).
//
// r8 LESSON: fusing pack_adj as 128 tail blocks serialized 8M ballots
// (0.5 blocks/CU, load latency exposed) -> prep 10->130us. r10 fix: fuse
// with the FULL 32768-block 1:1 mapping appended to prep's grid — same TLP
// as the standalone kernel, saves one launch + gap. maskT gets its own
// workspace slot so pack blocks cannot race prep's WT writes.

__device__ __forceinline__ float b2f(unsigned short u) {
    union { unsigned int i; float f; } v; v.i = ((unsigned int)u) << 16; return v.f;
}
__device__ __forceinline__ unsigned short f2b(float f) {
    union { float f; unsigned int i; } v; v.f = f;
    unsigned int u = v.i;
    u = (u + 0x7FFFu + ((u >> 16) & 1u)) >> 16;
    return (unsigned short)u;
}
// packed bf16 pair: lo=rne(a), hi=rne(b) — 1 instr replaces 2x f2b + pack
__device__ __forceinline__ unsigned int cvtpk(float a, float b) {
    unsigned int r;
    asm("v_cvt_pk_bf16_f32 %0, %1, %2" : "=v"(r) : "v"(a), "v"(b));
    return r;
}
__device__ __forceinline__ float blo(unsigned int u) {
    union { unsigned int i; float f; } v; v.i = u << 16; return v.f;
}
__device__ __forceinline__ float bhi(unsigned int u) {
    union { unsigned int i; float f; } v; v.i = u & 0xFFFF0000u; return v.f;
}
__device__ __forceinline__ void glds16(const void* g, const void* l) {
    __builtin_amdgcn_global_load_lds(
        (const __attribute__((address_space(1))) unsigned int*)g,
        (__attribute__((address_space(3))) unsigned int*)l, 16, 0, 0);
}

__device__ __forceinline__ void cvt8(const void* in, unsigned short* out,
                                     int f, int grp) {
    if (f) {
        ((ushort4*)out)[grp * 2]     = ((const ushort4*)in)[grp * 2];
        ((ushort4*)out)[grp * 2 + 1] = ((const ushort4*)in)[grp * 2 + 1];
    } else {
        const float4* p = (const float4*)in + (size_t)grp * 2;
        float4 a = p[0], b = p[1];
        ushort4 o0, o1;
        o0.x = f2b(a.x); o0.y = f2b(a.y); o0.z = f2b(a.z); o0.w = f2b(a.w);
        o1.x = f2b(b.x); o1.y = f2b(b.y); o1.z = f2b(b.z); o1.w = f2b(b.w);
        ((ushort4*)out)[grp * 2]     = o0;
        ((ushort4*)out)[grp * 2 + 1] = o1;
    }
}

// prep_all: single launch replacing prep+conv8+t2+zero+pack_adj.
// Blocks: [0,4096) x-convert | [4096,4352) W transpose | [4352,4416) zero f1/f2
//         | 4416 smalls+flag | [4417,4433) W_act transpose
//         | [4433,37201) pack_adj, 1 ballot-round per block (FULL 32768-block
//           TLP preserved — r8's 128-block version was ~100us slower).
__global__ __launch_bounds__(256) void prep_all(
        const unsigned int* __restrict__ x4,
        const void* __restrict__ x, const void* __restrict__ W,
        const void* __restrict__ Wact,
        const void* __restrict__ a1, const void* __restrict__ a2,
        const void* __restrict__ bact,
        const int* __restrict__ adj,
        unsigned short* __restrict__ xb, unsigned short* __restrict__ WT,
        unsigned short* __restrict__ WactT,
        unsigned short* __restrict__ a1b, unsigned short* __restrict__ a2b,
        unsigned short* __restrict__ bactb,
        int* __restrict__ flag, float4* __restrict__ fz,
        unsigned int* __restrict__ maskT) {
    __shared__ unsigned int tile[64 * 65];
    __shared__ int sflag;
    int tid = threadIdx.x;
    int bid = blockIdx.x;
    if (bid >= 4433) {                                // fused pack_adj, 1:1
        int gid = (bid - 4433) * 256 + tid;
        int lane = tid & 63;
        unsigned long long m = __ballot(adj[gid] > 0);
        if (lane == 0) {
            int lin = gid >> 6;       // (b*1024+n)*16 + m0/64
            int mw = (lin & 15) * 2;
            int bn = lin >> 4;
            int b = bn >> 10, n = bn & 1023;
            maskT[(size_t)(b * 32 + mw) * 1024 + n]     = (unsigned int)m;
            maskT[(size_t)(b * 32 + mw + 1) * 1024 + n] = (unsigned int)(m >> 32);
        }
        return;
    }
    if (bid >= 4352 && bid < 4416) {                  // zero f1/f2 (256 KB)
        fz[(bid - 4352) * 256 + tid] = float4{0.f, 0.f, 0.f, 0.f};
        return;
    }
    if (tid < 64) {                                   // per-block dtype detect
        unsigned int wv = x4[tid];
        unsigned int e = (wv >> 7) & 0xFF;
        unsigned long long m = __ballot(e >= 100 && e <= 140);
        if (tid == 0) sflag = (__popcll(m) >= 48) ? 1 : 0;
    }
    __syncthreads();
    int f = sflag;

    if (bid < 4096) {                                 // x -> xb bf16
        cvt8(x, xb, f, bid * 256 + tid);
        return;
    }
    if (bid == 4416) {                                // smalls + flag publish
        if (tid == 0) flag[0] = f;
        if (tid < 128) cvt8(a1, a1b, f, tid);
        else           cvt8(a2, a2b, f, tid - 128);
        if (tid < 8)   cvt8(bact, bactb, f, tid);
        return;
    }
    // LDS-tiled transpose: W (256 blocks, C=256) or W_act (16 blocks, C=64).
    const void* in; unsigned short* out; int C, bt, c0, r0;
    if (bid < 4352) {
        int lb = bid - 4096;
        in = W; out = WT; C = 256;
        c0 = (lb & 3) * 64;
        r0 = ((lb >> 2) & 15) * 64;
        bt = lb >> 6;
    } else {
        int lb = bid - 4417;
        in = Wact; out = WactT; C = 64;
        c0 = 0; r0 = lb * 64; bt = 0;
    }
    int rl = tid >> 2;
    int cc = (tid & 3) * 16;
    size_t ibase = ((size_t)bt * 1024 + (r0 + rl)) * C + c0 + cc;
    unsigned short v[16];
    if (f) {
        const unsigned short* p = (const unsigned short*)in + ibase;
        short8 a = *(const short8*)p;
        short8 b = *(const short8*)(p + 8);
#pragma unroll
        for (int j = 0; j < 8; j++) { v[j] = (unsigned short)a[j]; v[8 + j] = (unsigned short)b[j]; }
    } else {
        const float* p = (const float*)in + ibase;
#pragma unroll
        for (int j = 0; j < 16; j++) v[j] = f2b(p[j]);
    }
#pragma unroll
    for (int j = 0; j < 16; j++)
        tile[(cc + j) * 65 + rl] = v[j];
    __syncthreads();
    int cl = tid >> 2;
    int rch = (tid & 3) * 16;
    unsigned short o[16];
#pragma unroll
    for (int j = 0; j < 16; j++)
        o[j] = (unsigned short)tile[cl * 65 + rch + j];
    unsigned short* op = out + ((size_t)bt * C + (c0 + cl)) * 1024 + r0 + rch;
#pragma unroll
    for (int q = 0; q < 4; q++) {
        ushort4 s; s.x = o[q*4]; s.y = o[q*4+1]; s.z = o[q*4+2]; s.w = o[q*4+3];
        ((ushort4*)op)[q] = s;
    }
}

// K1: Wh = x @ W[h] -> WhF frag-tile bf16 (32x32 layout). Epilogue also
// accumulates f1 = Wh.a1, f2 = Wh.a2 (pre-scaled by log2e) via shfl+atomics.
// Config = r3 best (128x128 tile, BK=64, grid dim3(8,64), XCD swizzle:
// FETCH 16.6MB verified). Static-array double-buffer (r7: 43->41us).
// CLOSED at ~41-43us: runs ~420 TF, ABOVE the m97-structure small-problem
// reference curve (m102: 320 TF @ 16 GFLOP). Do not re-attempt within-block
// pipelining with runtime indices (r4) or smaller tiles (r5).
__global__ __launch_bounds__(256) void k1_gemm(
        const unsigned short* __restrict__ x,
        const unsigned short* __restrict__ WT,      // [H][E=256][K=1024]
        unsigned short* __restrict__ WhF,
        const unsigned short* __restrict__ a1b,
        const unsigned short* __restrict__ a2b,
        float* __restrict__ f1, float* __restrict__ f2) {
    __shared__ unsigned short smA0[16 * 512];       // 16KB each
    __shared__ unsigned short smA1[16 * 512];
    __shared__ unsigned short smB0[16 * 512];
    __shared__ unsigned short smB1[16 * 512];
    int tid = threadIdx.x;
    int w = tid >> 6, lane = tid & 63;
    int lr = lane & 15, lq = lane >> 4;
    int lin = blockIdx.x + 8 * blockIdx.y;      // HW dispatch-linear id
    int xcd = lin & 7, kk = lin >> 3;
    int ct = kk >> 3;                           // col tile 0..7 (h, e-half)
    int rt = xcd * 8 + (kk & 7);                // row tile 0..63 (b = xcd)
    int col0 = ct * 128;
    int row0 = rt * 128;
    int h = col0 >> 8;
    int e_base = col0 & 255;
    int b = row0 >> 10;
    int m_base = row0 & 1023;
    int wr = w >> 1, wc = w & 1;

    f32x4 acc[4][4] = {};

    // stage one BK=64 tile pair (16KB A + 16KB B); 8 glds16 per thread
    auto stage = [&](unsigned short* dA, unsigned short* dB, int k0) {
#pragma unroll
        for (int s = 0; s < 4; s++) {
            int g = 4 * w + s;                  // g = kh*8 + rb
            int rb = g & 7, kh = g >> 3;
            const unsigned short* srcA =
                x + (size_t)(row0 + rb * 16 + lr) * 1024 + k0 + kh * 32 + lq * 8;
            glds16(srcA, dA + g * 512);
            const unsigned short* srcB =
                WT + (size_t)(h * 256 + e_base + rb * 16 + lr) * 1024
                   + k0 + kh * 32 + lq * 8;
            glds16(srcB, dB + g * 512);
        }
    };
    auto compute = [&](const unsigned short* sA, const unsigned short* sB) {
#pragma unroll
        for (int kh = 0; kh < 2; kh++) {
            short8 af[4], bf[4];
#pragma unroll
            for (int i = 0; i < 4; i++)
                af[i] = *(const short8*)&sA[(kh * 8 + wr * 4 + i) * 512 + lane * 8];
#pragma unroll
            for (int j = 0; j < 4; j++)
                bf[j] = *(const short8*)&sB[(kh * 8 + wc * 4 + j) * 512 + lane * 8];
#pragma unroll
            for (int i = 0; i < 4; i++)
#pragma unroll
                for (int j = 0; j < 4; j++)
                    acc[i][j] = __builtin_amdgcn_mfma_f32_16x16x32_bf16(
                        af[i], bf[j], acc[i][j], 0, 0, 0);
        }
    };

    stage(smA0, smB0, 0);
    __syncthreads();                            // buf0 ready
    for (int t = 0; t < 16; t += 2) {
        stage(smA1, smB1, (t + 1) * 64);        // t+1 <= 15 always
        compute(smA0, smB0);
        __syncthreads();                        // drain buf1 loads + LDS sync
        if (t + 2 < 16) stage(smA0, smB0, (t + 2) * 64);
        compute(smA1, smB1);
        __syncthreads();
    }

    // Epilogue 1: WhF frag-tile stores (32x32 layout).
    int hb = h * 8 + b;
#pragma unroll
    for (int i = 0; i < 4; i++) {
#pragma unroll
        for (int j = 0; j < 4; j++) {
            int e = e_base + (wc * 4 + j) * 16 + lr;
            int et = e >> 5, e31 = e & 31;
            int m16 = (m_base >> 4) + wr * 4 + i;
            ushort4 vs;
            vs.x = f2b(acc[i][j][0]);
            vs.y = f2b(acc[i][j][1]);
            vs.z = f2b(acc[i][j][2]);
            vs.w = f2b(acc[i][j][3]);
            size_t idx = ((size_t)((hb * 8 + et) * 64 + m16) * 512)
                         + ((lq >> 1) * 32 + e31) * 8 + (lq & 1) * 4;
            *(ushort4*)&WhF[idx] = vs;
        }
    }

    // Epilogue 2: f1/f2 partials via shfl-reduce over the 16-lane e-groups.
    const float LOG2E = 1.44269504f;
    float a1v[4], a2v[4];
#pragma unroll
    for (int j = 0; j < 4; j++) {
        int e = e_base + (wc * 4 + j) * 16 + lr;
        a1v[j] = b2f(a1b[h * 256 + e]);
        a2v[j] = b2f(a2b[h * 256 + e]);
    }
#pragma unroll
    for (int i = 0; i < 4; i++) {
#pragma unroll
        for (int reg = 0; reg < 4; reg++) {
            float s1 = 0.f, s2 = 0.f;
#pragma unroll
            for (int j = 0; j < 4; j++) {
                s1 += acc[i][j][reg] * a1v[j];
                s2 += acc[i][j][reg] * a2v[j];
            }
            s1 += __shfl_xor(s1, 1, 64); s2 += __shfl_xor(s2, 1, 64);
            s1 += __shfl_xor(s1, 2, 64); s2 += __shfl_xor(s2, 2, 64);
            s1 += __shfl_xor(s1, 4, 64); s2 += __shfl_xor(s2, 4, 64);
            s1 += __shfl_xor(s1, 8, 64); s2 += __shfl_xor(s2, 8, 64);
            if (lr == 0) {
                int m = m_base + (wr * 4 + i) * 16 + lq * 4 + reg;
                atomicAdd(&f1[hb * 1024 + m], s1 * LOG2E);
                atomicAdd(&f2[hb * 1024 + m], s2 * LOG2E);
            }
        }
    }
}

// K2: masked-softmax attention + P@Wh + ELU -> feat bf16.
// Block = 512 thr = 8 waves = 2 row-groups (64 rows) x 4 e-quarter waves.
// The 4 q-waves of a row-group SPLIT the 32 softmax columns (4 p/lane/iter)
// and exchange the bf16 P-tile through a double-buffered LDS tile. cvt_pk
// packs p-pairs in one instr; den accumulates the ROUNDED p halves.
// m-loop HAND-UNROLLED 2x (named bufA/bufB, literal ptile idx — rule #20).
// s_setprio(1/0) around MFMA clusters (T5: produce/consume wave role-split).
__global__ __launch_bounds__(512, 4) void k2_attn(
        const unsigned short* __restrict__ WhF,
        const unsigned int* __restrict__ maskT,     // [8][32][1024]
        const float* __restrict__ f1, const float* __restrict__ f2,
        unsigned short* __restrict__ feat) {
    __shared__ unsigned short ptile[2][2][32][40];  // [buf][rg][row][col pad40]
    __shared__ float dred[2][4][32];                // [rg][q][row]
    int tid = threadIdx.x;
    int w = tid >> 6, lane = tid & 63;
    int q = w & 3, wrg = w >> 2;
    int l5 = lane >> 5, l31 = lane & 31;
    int bid = blockIdx.x;
    int xcd = bid & 7, idx = bid >> 3;          // idx 0..63
    int hb = xcd + 8 * (idx >> 4);              // 4 hb per XCD, same b = xcd
    int rgb = idx & 15;                         // 16 row-blocks of 64
    int n0 = rgb * 64 + wrg * 32;
    int h = hb >> 3, b = hb & 7;
    int row = n0 + l31;
    float f1n = f1[hb * 1024 + row];            // already *log2e
    const unsigned short* whb = WhF + (size_t)(hb * 8 + q * 2) * 64 * 512
                                + lane * 8;
    const unsigned int* mrow = maskT + (size_t)b * 32 * 1024 + row;
    const float* f2p = f2 + hb * 1024 + q * 8 + l5 * 4;   // this lane's 4 cols
    int cshift = q * 8 + l5 * 4;                // col base within 32-block

    f32x16 acc[2] = {};                         // e = q*64 + et*32 + l31
    float den = 0.f;

    short8 bufA[2][2], bufB[2][2];              // [et][ks] — named, static idx
#pragma unroll
    for (int et = 0; et < 2; et++)
#pragma unroll
        for (int ks = 0; ks < 2; ks++)
            bufA[et][ks] = *(const short8*)(whb + (size_t)(et * 64 + ks) * 512);

    unsigned int mw = mrow[0];
    float4 fv = *(const float4*)f2p;

    for (int mb = 0; mb < 32; mb += 2) {
        // ===== even block mb: produce->ptile[0], compute with bufA =====
        {
            float fvv[4] = {fv.x, fv.y, fv.z, fv.w};
            unsigned int mloc = mw >> cshift;
            float pv[4];
#pragma unroll
            for (int j = 0; j < 4; j++) {
                float t_ = f1n + fvv[j];
                float e_ = fmaxf(t_, 0.2f * t_);               // leaky relu
                pv[j] = ((mloc >> j) & 1u) ? exp2f(e_) : 0.f;
            }
            unsigned int r0 = cvtpk(pv[0], pv[1]);
            unsigned int r1 = cvtpk(pv[2], pv[3]);
            den += (blo(r0) + bhi(r0)) + (blo(r1) + bhi(r1));
            uint2 pr; pr.x = r0; pr.y = r1;
            *(uint2*)&ptile[0][wrg][l31][cshift] = pr;
            // prefetch mask/f2 for block mb+1 (always exists: mb+1 <= 31)
            mw = mrow[(size_t)(mb + 1) * 1024];
            fv = *(const float4*)(f2p + (mb + 1) * 32);
            __syncthreads();
            short8 af0 = *(const short8*)&ptile[0][wrg][l31][l5 * 8];
            short8 af1 = *(const short8*)&ptile[0][wrg][l31][16 + l5 * 8];
            // prefetch WhF frags for block mb+1 into bufB
            int m16n = (mb + 1) * 2;
#pragma unroll
            for (int et = 0; et < 2; et++)
#pragma unroll
                for (int ks = 0; ks < 2; ks++)
                    bufB[et][ks] =
                        *(const short8*)(whb + (size_t)(et * 64 + m16n + ks) * 512);
            __builtin_amdgcn_s_setprio(1);
#pragma unroll
            for (int et = 0; et < 2; et++) {
                acc[et] = __builtin_amdgcn_mfma_f32_32x32x16_bf16(
                    af0, bufA[et][0], acc[et], 0, 0, 0);
                acc[et] = __builtin_amdgcn_mfma_f32_32x32x16_bf16(
                    af1, bufA[et][1], acc[et], 0, 0, 0);
            }
            __builtin_amdgcn_s_setprio(0);
        }
        // ===== odd block mb+1: produce->ptile[1], compute with bufB =====
        {
            float fvv[4] = {fv.x, fv.y, fv.z, fv.w};
            unsigned int mloc = mw >> cshift;
            float pv[4];
#pragma unroll
            for (int j = 0; j < 4; j++) {
                float t_ = f1n + fvv[j];
                float e_ = fmaxf(t_, 0.2f * t_);               // leaky relu
                pv[j] = ((mloc >> j) & 1u) ? exp2f(e_) : 0.f;
            }
            unsigned int r0 = cvtpk(pv[0], pv[1]);
            unsigned int r1 = cvtpk(pv[2], pv[3]);
            den += (blo(r0) + bhi(r0)) + (blo(r1) + bhi(r1));
            uint2 pr; pr.x = r0; pr.y = r1;
            *(uint2*)&ptile[1][wrg][l31][cshift] = pr;
            // prefetch mask/f2 for block mb+2 (if any)
            if (mb < 30) {
                mw = mrow[(size_t)(mb + 2) * 1024];
                fv = *(const float4*)(f2p + (mb + 2) * 32);
            }
            __syncthreads();
            short8 af0 = *(const short8*)&ptile[1][wrg][l31][l5 * 8];
            short8 af1 = *(const short8*)&ptile[1][wrg][l31][16 + l5 * 8];
            if (mb < 30) {                      // prefetch frags for mb+2
                int m16n = (mb + 2) * 2;
#pragma unroll
                for (int et = 0; et < 2; et++)
#pragma unroll
                    for (int ks = 0; ks < 2; ks++)
                        bufA[et][ks] =
                            *(const short8*)(whb + (size_t)(et * 64 + m16n + ks) * 512);
            }
            __builtin_amdgcn_s_setprio(1);
#pragma unroll
            for (int et = 0; et < 2; et++) {
                acc[et] = __builtin_amdgcn_mfma_f32_32x32x16_bf16(
                    af0, bufB[et][0], acc[et], 0, 0, 0);
                acc[et] = __builtin_amdgcn_mfma_f32_32x32x16_bf16(
                    af1, bufB[et][1], acc[et], 0, 0, 0);
            }
            __builtin_amdgcn_s_setprio(0);
        }
    }

    // den: lane has rows l31, cols cshift..+3; fold l5 halves, then 4 q-waves.
    den += __shfl_xor(den, 32, 64);
    if (l5 == 0) dred[wrg][q][l31] = den;
    __syncthreads();
    float denf = dred[wrg][0][l31] + dred[wrg][1][l31]
               + dred[wrg][2][l31] + dred[wrg][3][l31];

#pragma unroll
    for (int reg = 0; reg < 16; reg++) {
        int r = (reg & 3) + 8 * (reg >> 2) + 4 * l5;   // C-layout row (0..31)
        float dr = __shfl(denf, r, 64);
        float rdr = 1.0f / dr;
        int nn = n0 + r;
#pragma unroll
        for (int et = 0; et < 2; et++) {
            int e = q * 64 + et * 32 + l31;
            float v = acc[et][reg] * rdr;
            float o = v > 0.f ? v : __expf(v) - 1.f;   // elu
            feat[(size_t)(b * 1024 + nn) * 1024 + h * 256 + e] = f2b(o);
        }
    }
}

// K3: out = feat @ W_act + b_act  (M=8192, K=1024, N=64), out dtype per flag.
// Static-array double-buffer (a0/a1/b0/b1 named, hand-unrolled 2x).
__global__ __launch_bounds__(256) void k3_out(
        const unsigned short* __restrict__ feat,
        const unsigned short* __restrict__ WactT,   // [64][1024]
        const unsigned short* __restrict__ bact,
        void* __restrict__ out, const int* __restrict__ flag) {
    __shared__ unsigned short sa0[2 * 512], sa1[2 * 512];
    __shared__ unsigned short sb0[4 * 512], sb1[4 * 512];
    int tid = threadIdx.x;
    int w = tid >> 6, lane = tid & 63;
    int lr = lane & 15, lq = lane >> 4;
    int row0 = blockIdx.x * 32;
    int g = w & 1, ch = w >> 1;
    int bf16out = *flag;
    f32x4 acc[2] = {};

    auto stage = [&](unsigned short* dA, unsigned short* dB, int k0) {
        if (w < 2) {
            const unsigned short* src =
                feat + (size_t)(row0 + w * 16 + lr) * 1024 + k0 + lq * 8;
            glds16(src, dA + w * 512);
        } else {
#pragma unroll
            for (int s = 0; s < 2; s++) {
                int t = (w - 2) * 2 + s;
                const unsigned short* src =
                    WactT + (size_t)(t * 16 + lr) * 1024 + k0 + lq * 8;
                glds16(src, dB + t * 512);
            }
        }
    };
    auto compute = [&](const unsigned short* sA, const unsigned short* sB) {
        short8 af = *(const short8*)&sA[g * 512 + lane * 8];
#pragma unroll
        for (int j = 0; j < 2; j++) {
            short8 bf = *(const short8*)&sB[(ch * 2 + j) * 512 + lane * 8];
            acc[j] = __builtin_amdgcn_mfma_f32_16x16x32_bf16(af, bf, acc[j], 0, 0, 0);
        }
    };

    stage(sa0, sb0, 0);
    __syncthreads();
    for (int t = 0; t < 32; t += 2) {
        stage(sa1, sb1, (t + 1) * 32);          // t+1 <= 31 always
        compute(sa0, sb0);
        __syncthreads();
        if (t + 2 < 32) stage(sa0, sb0, (t + 2) * 32);
        compute(sa1, sb1);
        __syncthreads();
    }
#pragma unroll
    for (int j = 0; j < 2; j++) {
        int col = ch * 32 + j * 16 + lr;
        float bv = b2f(bact[col]);
#pragma unroll
        for (int rr = 0; rr < 4; rr++) {
            int r = row0 + g * 16 + lq * 4 + rr;
            float val = acc[j][rr] + bv;
            if (bf16out) ((unsigned short*)out)[(size_t)r * 64 + col] = f2b(val);
            else         ((float*)out)[(size_t)r * 64 + col] = val;
        }
    }
}

extern "C" void kernel_launch(void* const* d_in, const int* in_sizes, int n_in,
                              void* d_out, int out_size, void* d_ws, size_t ws_size,
                              hipStream_t stream) {
    const void* x    = d_in[0];
    const int*  adj  = (const int*)d_in[1];
    const void* W    = d_in[2];
    const void* a1   = d_in[3];
    const void* a2   = d_in[4];
    const void* Wact = d_in[5];
    const void* bact = d_in[6];

    char* ws = (char*)d_ws;
    unsigned short* WhF   = (unsigned short*)(ws);               // 16 MB  frag-tile
    unsigned short* xb    = (unsigned short*)(ws + 16777216);    // 16 MB  (== feat)
    unsigned short* feat  = (unsigned short*)(ws + 16777216);    // 16 MB  [8192][1024]
    unsigned short* WT    = (unsigned short*)(ws + 33554432);    //  2 MB  [4][256][1024]
    unsigned short* WactT = (unsigned short*)(ws + 35651584);    // 128 KB [64][1024]
    float*          f1    = (float*)(ws + 35782656);             // 128 KB [32][1024]
    float*          f2    = (float*)(ws + 35913728);             // 128 KB [32][1024]
    unsigned short* a1b   = (unsigned short*)(ws + 36044800);    // 2 KB
    unsigned short* a2b   = (unsigned short*)(ws + 36046848);    // 2 KB
    unsigned short* bactb = (unsigned short*)(ws + 36048896);    // 128 B
    int*            flag  = (int*)(ws + 36049024);               // 16 B
    unsigned int*   maskT = (unsigned int*)(ws + 36700160);      //  1 MB (own slot,
                                                                 //  no WT alias)
    if (ws_size < (size_t)37748736) return;

    prep_all<<<37201, 256, 0, stream>>>((const unsigned int*)x, x, W, Wact,
                                        a1, a2, bact, adj, xb, WT, WactT,
                                        a1b, a2b, bactb, flag, (float4*)f1,
                                        maskT);
    k1_gemm<<<dim3(8, 64), 256, 0, stream>>>(xb, WT, WhF, a1b, a2b, f1, f2);
    k2_attn<<<512, 512, 0, stream>>>(WhF, maskT, f1, f2, feat);
    k3_out<<<256, 256, 0, stream>>>(feat, WactT, bactb, d_out, flag);
}